// Round 2
// baseline (250.613 us; speedup 1.0000x reference)
//
#include <hip/hip_runtime.h>

#define IN_FEAT 1024
#define OUT_FEAT 1024
#define NSAMP 8192
#define KBASE 1024
#define KSPL 8192
// fp6 tiled layout: [rowblk(128)][kb(64)][quad(4)][row(128)][24B]
#define GRANB 24                     /* bytes per 32-elem fp6 granule */
#define KBBYTES (4 * 128 * GRANB)    /* 12288 B: one k-block (K=128) for 128 rows */
#define RBSTRIDE (64L * KBBYTES)     /* 786432 B per 128-row block */

typedef __bf16 v8bf __attribute__((ext_vector_type(8)));
typedef float v4f __attribute__((ext_vector_type(4)));
typedef float v32f __attribute__((ext_vector_type(32)));
typedef int v8i __attribute__((ext_vector_type(8)));
typedef int v6i __attribute__((ext_vector_type(6)));
typedef unsigned long long u64;

__device__ __forceinline__ void load16_lds(const void* g, void* l) {
  __builtin_amdgcn_global_load_lds(
      (const __attribute__((address_space(1))) void*)g,
      (__attribute__((address_space(3))) void*)l, 16, 0, 0);
}

// fp6 e2m3 encode (round-nearest): e=0/1 step .125 to 1.875; e=2 step .25; e=3 step .5
__device__ __forceinline__ unsigned enc_e2m3(float v) {
  unsigned s = 0u;
  float a = v;
  if (a < 0.f) { s = 32u; a = -a; }
  unsigned code;
  if (a < 1.9375f)      code = (unsigned)rintf(a * 8.0f);
  else if (a < 3.875f)  code = 16u + (unsigned)rintf((a - 2.0f) * 4.0f);
  else if (a < 7.25f)   code = 24u + (unsigned)rintf((a - 4.0f) * 2.0f);
  else                  code = 31u;
  return s | code;
}

// Pack 32 fp32 -> 32 fp6 e2m3 (24 B), HW pk32 convert if available.
__device__ __forceinline__ void pack32_fp6(const float* vals, unsigned char* dst) {
#if __has_builtin(__builtin_amdgcn_cvt_scalef32_pk32_fp6_f32)
  v32f v;
#pragma unroll
  for (int e = 0; e < 32; ++e) v[e] = vals[e];
  v6i r = __builtin_amdgcn_cvt_scalef32_pk32_fp6_f32(v, 1.0f);
  u64* dq = reinterpret_cast<u64*>(dst);
  dq[0] = (u64)(unsigned)r[0] | ((u64)(unsigned)r[1] << 32);
  dq[1] = (u64)(unsigned)r[2] | ((u64)(unsigned)r[3] << 32);
  dq[2] = (u64)(unsigned)r[4] | ((u64)(unsigned)r[5] << 32);
#else
  u64 w0 = 0, w1 = 0, w2 = 0;
#pragma unroll
  for (int e = 0; e < 32; ++e) {
    u64 c = enc_e2m3(vals[e]);
    int bp = 6 * e;
    if (bp < 64) {
      w0 |= c << bp;
      if (bp > 58) w1 |= c >> (64 - bp);
    } else if (bp < 128) {
      w1 |= c << (bp - 64);
      if (bp > 122) w2 |= c >> (128 - bp);
    } else {
      w2 |= c << (bp - 128);
    }
  }
  u64* dq = reinterpret_cast<u64*>(dst);
  dq[0] = w0; dq[1] = w1; dq[2] = w2;
#endif
}

// Granule builder (unchanged). A-part uses a 256-entry LUT over the fractional
// spline coordinate u; 4 consecutive nonzero bases, fp6 codes (x4 prescale)
// shifted to slot t0-3 in the 48-bit per-i segment.
__global__ __launch_bounds__(256) void build_AB(const float* __restrict__ x,
                                                const float* __restrict__ grid,
                                                const float* __restrict__ bw,
                                                const float* __restrict__ sw,
                                                const float* __restrict__ sc,
                                                __bf16* __restrict__ A1,
                                                unsigned char* __restrict__ A2,
                                                __bf16* __restrict__ B1,
                                                unsigned char* __restrict__ B2) {
  if (blockIdx.x < 8192) {
    __shared__ unsigned lut[256];
    {
      float u = ((float)threadIdx.x + 0.5f) * (1.0f / 256.0f);
      float u2 = u * u, u3 = u2 * u;
      float om = 1.0f - u;
      const float s = 4.0f / 6.0f;
      unsigned c0 = enc_e2m3(om * om * om * s);
      unsigned c1 = enc_e2m3((3.f * u3 - 6.f * u2 + 4.f) * s);
      unsigned c2 = enc_e2m3((-3.f * u3 + 3.f * u2 + 3.f * u + 1.f) * s);
      unsigned c3 = enc_e2m3(u3 * s);
      lut[threadIdx.x] = c0 | (c1 << 6) | (c2 << 12) | (c3 << 18);
    }
    __syncthreads();

    int g = blockIdx.x * 256 + threadIdx.x;
    int r = g & 127;
    int quad = (g >> 7) & 3;
    int kb = (g >> 9) & 63;
    int rb = g >> 15;
    long n = rb * 128 + r;
    int i0 = kb * 16 + quad * 4;

    float4 xv4 = *reinterpret_cast<const float4*>(x + n * IN_FEAT + i0);
    float xs[4] = {xv4.x, xv4.y, xv4.z, xv4.w};

    union { __bf16 h[4]; u64 u; } a1;
#pragma unroll
    for (int j = 0; j < 4; ++j)
      a1.h[j] = (__bf16)(xs[j] / (1.0f + __expf(-xs[j])));
    *reinterpret_cast<u64*>(A1 + n * IN_FEAT + i0) = a1.u;

    u64 w0 = 0, w1 = 0, w2 = 0;
#pragma unroll
    for (int j = 0; j < 4; ++j) {
      float p = (xs[j] + 2.2f) * 2.5f;
      float fl = floorf(p);
      int t0 = (int)fl;
      int idx = (int)((p - fl) * 256.0f) & 255;
      u64 codes = (u64)lut[idx];
      int sh = 6 * t0 - 18; // place c0 at slot t0-3
      u64 seg = (sh >= 0) ? (codes << sh) : (codes >> (-sh));
      seg = ((unsigned)t0 <= 10u) ? (seg & 0xFFFFFFFFFFFFULL) : 0ULL;
      if (j == 0) w0 |= seg;
      else if (j == 1) { w0 |= seg << 48; w1 |= seg >> 16; }
      else if (j == 2) { w1 |= seg << 32; w2 |= seg >> 32; }
      else             { w2 |= seg << 16; }
    }
    u64* dq = reinterpret_cast<u64*>(
        A2 + rb * RBSTRIDE + kb * KBBYTES + quad * (128 * GRANB) + r * GRANB);
    dq[0] = w0; dq[1] = w1; dq[2] = w2;
  } else {
    int g = (blockIdx.x - 8192) * 256 + threadIdx.x;
    int r = g & 127;
    int quad = (g >> 7) & 3;
    int kb = (g >> 9) & 63;
    int ob = g >> 15;
    long o = ob * 128 + r;
    int i0 = kb * 16 + quad * 4;

    float4 bw4 = *reinterpret_cast<const float4*>(bw + o * IN_FEAT + i0);
    union { __bf16 h[4]; u64 u; } b1;
    b1.h[0] = (__bf16)bw4.x; b1.h[1] = (__bf16)bw4.y;
    b1.h[2] = (__bf16)bw4.z; b1.h[3] = (__bf16)bw4.w;
    *reinterpret_cast<u64*>(B1 + o * IN_FEAT + i0) = b1.u;

    float vals[32];
    float4 sc4 = *reinterpret_cast<const float4*>(sc + o * IN_FEAT + i0);
    float scs[4] = {sc4.x, sc4.y, sc4.z, sc4.w};
#pragma unroll
    for (int j = 0; j < 4; ++j) {
      float scale = scs[j] * 256.0f; // 2^8, undone by scaleB=119
      const float4* sp =
          reinterpret_cast<const float4*>(sw + (o * IN_FEAT + i0 + j) * 8);
      float4 p0 = sp[0];
      float4 p1 = sp[1];
      vals[j * 8 + 0] = p0.x * scale; vals[j * 8 + 1] = p0.y * scale;
      vals[j * 8 + 2] = p0.z * scale; vals[j * 8 + 3] = p0.w * scale;
      vals[j * 8 + 4] = p1.x * scale; vals[j * 8 + 5] = p1.y * scale;
      vals[j * 8 + 6] = p1.z * scale; vals[j * 8 + 7] = p1.w * scale;
    }
    pack32_fp6(vals, B2 + (long)ob * RBSTRIDE + kb * KBBYTES +
                         quad * (128 * GRANB) + r * GRANB);
  }
}

// Pipelined fused GEMM (T3+T4+T5 + T1 swizzle):
//  - 512 threads = 8 waves (2M x 4N), 128x128 tile, wave tile 64x32.
//  - Full LDS double-buffer (2 x 64 KB): per iter stage 2 fp6 k-blocks (K=256)
//    + K=32 bf16 sub-tiles into the NEXT buffer (8 global_load_lds / thread).
//  - Counted s_waitcnt vmcnt(8): waits only the PREVIOUS tile's 8 loads; the
//    just-issued 8 stay in flight across the barrier and the whole compute
//    phase (never drain to 0 in the main loop).
//  - lgkmcnt(0) before the compute->stage barrier: closes the WAR window where
//    a sunk MFMA leaves a ds_read in flight on the buffer the next stage()
//    overwrites.
//  - setprio(1) around MFMA clusters; XCD-chunked bm swizzle (512 % 8 == 0,
//    bijective) keeps 4 A-panels (3.1 MB) L2-resident per XCD.
__global__ __launch_bounds__(512, 2) void gemm_fused(const unsigned char* __restrict__ A2,
                                                     const unsigned char* __restrict__ B2,
                                                     const __bf16* __restrict__ A1,
                                                     const __bf16* __restrict__ B1,
                                                     float* __restrict__ C) {
  // per-buffer layout: As6 [0,24576) | Bs6 [24576,49152) | As1 [49152,57344)
  //                    | Bs1 [57344,65536); two buffers = 128 KiB.
  __shared__ __attribute__((aligned(16))) unsigned char smem[131072];

  const int tid = threadIdx.x;
  // XCD swizzle: flat 0..511, xcd = flat&7 owns bm strip [xcd*8, xcd*8+8).
  const int flat = blockIdx.y * gridDim.x + blockIdx.x;
  const int swz = (flat & 7) * 64 + (flat >> 3);
  const int bm = swz >> 3;  // 0..63
  const int bn = swz & 7;   // 0..7

  const int lane = tid & 63;
  const int w = tid >> 6;
  const int wm = (w >> 2) * 64;  // 2 row-halves of 64
  const int wn = (w & 3) * 32;   // 4 col-quarters of 32
  const int l16 = lane & 15;
  const int quad = lane >> 4;

  const unsigned char* gA6 = A2 + (long)bm * RBSTRIDE + tid * 16;
  const unsigned char* gB6 = B2 + (long)bn * RBSTRIDE + tid * 16;
  const __bf16* gA1 = A1 + (long)(bm * 128 + (tid >> 2)) * KBASE + (tid & 3) * 8;
  const __bf16* gB1 = B1 + (long)(bn * 128 + (tid >> 2)) * KBASE + (tid & 3) * 8;

  v4f acc[4][2] = {};

  auto stage = [&](int it) {
    unsigned char* db = smem + (size_t)(it & 1) * 65536;
    const long off6 = (long)it * (2 * KBBYTES);
#pragma unroll
    for (int t = 0; t < 3; ++t) {
      load16_lds(gA6 + off6 + t * 8192, db + tid * 16 + t * 8192);
      load16_lds(gB6 + off6 + t * 8192, db + 24576 + tid * 16 + t * 8192);
    }
    const int k0 = it * 32;
    load16_lds(gA1 + k0, db + 49152 + tid * 16);
    load16_lds(gB1 + k0, db + 57344 + tid * 16);
  };

  auto compute = [&](int it) {
    const unsigned char* db = smem + (size_t)(it & 1) * 65536;
    const unsigned char* aB0 = db + quad * (128 * GRANB) + (wm + l16) * GRANB;
    const unsigned char* bB0 = db + 24576 + quad * (128 * GRANB) + (wn + l16) * GRANB;
#pragma unroll
    for (int kb2 = 0; kb2 < 2; ++kb2) {
      const unsigned char* aB = aB0 + kb2 * KBBYTES;
      const unsigned char* bB = bB0 + kb2 * KBBYTES;
      v8i af[4], bfr[2];
#pragma unroll
      for (int mi = 0; mi < 4; ++mi) {
        const unsigned char* rb = aB + mi * 16 * GRANB;
        u64 a0 = *reinterpret_cast<const u64*>(rb);
        u64 a1v = *reinterpret_cast<const u64*>(rb + 8);
        u64 a2v = *reinterpret_cast<const u64*>(rb + 16);
        v8i f = {(int)a0, (int)(a0 >> 32), (int)a1v, (int)(a1v >> 32),
                 (int)a2v, (int)(a2v >> 32), 0, 0};
        af[mi] = f;
      }
#pragma unroll
      for (int ni = 0; ni < 2; ++ni) {
        const unsigned char* rb = bB + ni * 16 * GRANB;
        u64 b0 = *reinterpret_cast<const u64*>(rb);
        u64 b1v = *reinterpret_cast<const u64*>(rb + 8);
        u64 b2v = *reinterpret_cast<const u64*>(rb + 16);
        v8i f = {(int)b0, (int)(b0 >> 32), (int)b1v, (int)(b1v >> 32),
                 (int)b2v, (int)(b2v >> 32), 0, 0};
        bfr[ni] = f;
      }
      __builtin_amdgcn_s_setprio(1);
#pragma unroll
      for (int mi = 0; mi < 4; ++mi)
#pragma unroll
        for (int ni = 0; ni < 2; ++ni)
          // fmt 2 = fp6 e2m3 both; scaleA=125 (2^-2), scaleB=119 (2^-8)
          acc[mi][ni] = __builtin_amdgcn_mfma_scale_f32_16x16x128_f8f6f4(
              af[mi], bfr[ni], acc[mi][ni], 2, 2, 0, 125, 0, 119);
      __builtin_amdgcn_s_setprio(0);
    }
    {
      const __bf16* aP =
          reinterpret_cast<const __bf16*>(db + 49152) + (wm + l16) * 32 + quad * 8;
      const __bf16* bP =
          reinterpret_cast<const __bf16*>(db + 57344) + (wn + l16) * 32 + quad * 8;
      v8bf a1f[4], b1f[2];
#pragma unroll
      for (int t = 0; t < 4; ++t)
        a1f[t] = *reinterpret_cast<const v8bf*>(aP + t * 16 * 32);
#pragma unroll
      for (int t = 0; t < 2; ++t)
        b1f[t] = *reinterpret_cast<const v8bf*>(bP + t * 16 * 32);
      __builtin_amdgcn_s_setprio(1);
#pragma unroll
      for (int mi = 0; mi < 4; ++mi)
#pragma unroll
        for (int ni = 0; ni < 2; ++ni)
          acc[mi][ni] = __builtin_amdgcn_mfma_f32_16x16x32_bf16(
              a1f[mi], b1f[ni], acc[mi][ni], 0, 0, 0);
      __builtin_amdgcn_s_setprio(0);
    }
  };

#define VM_WAIT8() asm volatile("s_waitcnt vmcnt(8)" ::: "memory")
#define VM_WAIT0() asm volatile("s_waitcnt vmcnt(0)" ::: "memory")
#define LGKM0()    asm volatile("s_waitcnt lgkmcnt(0)" ::: "memory")
#define BARRIER()  asm volatile("s_barrier" ::: "memory")

  stage(0);
#pragma unroll 1
  for (int ip = 0; ip < 15; ++ip) {
    // even iteration: compute buf0, prefetch into buf1
    stage(2 * ip + 1);
    VM_WAIT8();
    BARRIER();
    compute(2 * ip);
    LGKM0();
    BARRIER();
    // odd iteration: compute buf1, prefetch into buf0
    stage(2 * ip + 2);
    VM_WAIT8();
    BARRIER();
    compute(2 * ip + 1);
    LGKM0();
    BARRIER();
  }
  // it = 30 (buf0) with final prefetch, then drained it = 31 (buf1)
  stage(31);
  VM_WAIT8();
  BARRIER();
  compute(30);
  LGKM0();
  BARRIER();
  VM_WAIT0();
  BARRIER();
  compute(31);

  // Epilogue: C/D layout col = lane&15, row = quad*4 + reg. Single write.
#pragma unroll
  for (int mi = 0; mi < 4; ++mi)
#pragma unroll
    for (int ni = 0; ni < 2; ++ni)
#pragma unroll
      for (int r = 0; r < 4; ++r) {
        int row = bm * 128 + wm + mi * 16 + quad * 4 + r;
        int col = bn * 128 + wn + ni * 16 + l16;
        C[(long)row * OUT_FEAT + col] = acc[mi][ni][r];
      }
}

extern "C" void kernel_launch(void* const* d_in, const int* in_sizes, int n_in,
                              void* d_out, int out_size, void* d_ws, size_t ws_size,
                              hipStream_t stream) {
  const float* x = (const float*)d_in[0];
  const float* bw = (const float*)d_in[1];
  const float* sw = (const float*)d_in[2];
  const float* sc = (const float*)d_in[3];
  const float* grid = (const float*)d_in[4];
  float* out = (float*)d_out;

  // ws: A1 bf16 16.8MB | A2 fp6 50.3MB | B1 bf16 2MB | B2 fp6 6.3MB
  __bf16* A1 = (__bf16*)d_ws;
  unsigned char* A2 = (unsigned char*)(A1 + (size_t)NSAMP * KBASE);
  __bf16* B1 = (__bf16*)(A2 + 64L * RBSTRIDE);
  unsigned char* B2 = (unsigned char*)(B1 + (size_t)OUT_FEAT * KBASE);

  build_AB<<<8192 + 1024, 256, 0, stream>>>(x, grid, bw, sw, sc, A1, A2, B1, B2);
  gemm_fused<<<dim3(NSAMP / 128, OUT_FEAT / 128), 512, 0, stream>>>(
      A2, B2, A1, B1, out);
}

// Round 4
// 244.918 us; speedup vs baseline: 1.0233x; 1.0233x over previous
//
#include <hip/hip_runtime.h>

#define IN_FEAT 1024
#define OUT_FEAT 1024
#define NSAMP 8192
#define KBASE 1024
#define KSPL 8192
// fp6 tiled layout: [rowblk(128)][kb(64)][quad(4)][row(128)][24B]
#define GRANB 24                     /* bytes per 32-elem fp6 granule */
#define KBBYTES (4 * 128 * GRANB)    /* 12288 B: one k-block (K=128) for 128 rows */
#define RBSTRIDE (64L * KBBYTES)     /* 786432 B per 128-row block */

typedef __bf16 v8bf __attribute__((ext_vector_type(8)));
typedef float v4f __attribute__((ext_vector_type(4)));
typedef float v16f __attribute__((ext_vector_type(16)));
typedef float v32f __attribute__((ext_vector_type(32)));
typedef int v8i __attribute__((ext_vector_type(8)));
typedef int v6i __attribute__((ext_vector_type(6)));
typedef unsigned long long u64;

__device__ __forceinline__ void load16_lds(const void* g, void* l) {
  __builtin_amdgcn_global_load_lds(
      (const __attribute__((address_space(1))) void*)g,
      (__attribute__((address_space(3))) void*)l, 16, 0, 0);
}

// fp6 e2m3 encode (round-nearest): e=0/1 step .125 to 1.875; e=2 step .25; e=3 step .5
__device__ __forceinline__ unsigned enc_e2m3(float v) {
  unsigned s = 0u;
  float a = v;
  if (a < 0.f) { s = 32u; a = -a; }
  unsigned code;
  if (a < 1.9375f)      code = (unsigned)rintf(a * 8.0f);
  else if (a < 3.875f)  code = 16u + (unsigned)rintf((a - 2.0f) * 4.0f);
  else if (a < 7.25f)   code = 24u + (unsigned)rintf((a - 4.0f) * 2.0f);
  else                  code = 31u;
  return s | code;
}

// Pack 32 fp32 -> 32 fp6 e2m3 (24 B), HW pk32 convert if available.
__device__ __forceinline__ void pack32_fp6(const float* vals, unsigned char* dst) {
#if __has_builtin(__builtin_amdgcn_cvt_scalef32_pk32_fp6_f32)
  v32f v;
#pragma unroll
  for (int e = 0; e < 32; ++e) v[e] = vals[e];
  v6i r = __builtin_amdgcn_cvt_scalef32_pk32_fp6_f32(v, 1.0f);
  u64* dq = reinterpret_cast<u64*>(dst);
  dq[0] = (u64)(unsigned)r[0] | ((u64)(unsigned)r[1] << 32);
  dq[1] = (u64)(unsigned)r[2] | ((u64)(unsigned)r[3] << 32);
  dq[2] = (u64)(unsigned)r[4] | ((u64)(unsigned)r[5] << 32);
#else
  u64 w0 = 0, w1 = 0, w2 = 0;
#pragma unroll
  for (int e = 0; e < 32; ++e) {
    u64 c = enc_e2m3(vals[e]);
    int bp = 6 * e;
    if (bp < 64) {
      w0 |= c << bp;
      if (bp > 58) w1 |= c >> (64 - bp);
    } else if (bp < 128) {
      w1 |= c << (bp - 64);
      if (bp > 122) w2 |= c >> (128 - bp);
    } else {
      w2 |= c << (bp - 128);
    }
  }
  u64* dq = reinterpret_cast<u64*>(dst);
  dq[0] = w0; dq[1] = w1; dq[2] = w2;
#endif
}

// Granule builder (unchanged).
__global__ __launch_bounds__(256) void build_AB(const float* __restrict__ x,
                                                const float* __restrict__ grid,
                                                const float* __restrict__ bw,
                                                const float* __restrict__ sw,
                                                const float* __restrict__ sc,
                                                __bf16* __restrict__ A1,
                                                unsigned char* __restrict__ A2,
                                                __bf16* __restrict__ B1,
                                                unsigned char* __restrict__ B2) {
  if (blockIdx.x < 8192) {
    __shared__ unsigned lut[256];
    {
      float u = ((float)threadIdx.x + 0.5f) * (1.0f / 256.0f);
      float u2 = u * u, u3 = u2 * u;
      float om = 1.0f - u;
      const float s = 4.0f / 6.0f;
      unsigned c0 = enc_e2m3(om * om * om * s);
      unsigned c1 = enc_e2m3((3.f * u3 - 6.f * u2 + 4.f) * s);
      unsigned c2 = enc_e2m3((-3.f * u3 + 3.f * u2 + 3.f * u + 1.f) * s);
      unsigned c3 = enc_e2m3(u3 * s);
      lut[threadIdx.x] = c0 | (c1 << 6) | (c2 << 12) | (c3 << 18);
    }
    __syncthreads();

    int g = blockIdx.x * 256 + threadIdx.x;
    int r = g & 127;
    int quad = (g >> 7) & 3;
    int kb = (g >> 9) & 63;
    int rb = g >> 15;
    long n = rb * 128 + r;
    int i0 = kb * 16 + quad * 4;

    float4 xv4 = *reinterpret_cast<const float4*>(x + n * IN_FEAT + i0);
    float xs[4] = {xv4.x, xv4.y, xv4.z, xv4.w};

    union { __bf16 h[4]; u64 u; } a1;
#pragma unroll
    for (int j = 0; j < 4; ++j)
      a1.h[j] = (__bf16)(xs[j] / (1.0f + __expf(-xs[j])));
    *reinterpret_cast<u64*>(A1 + n * IN_FEAT + i0) = a1.u;

    u64 w0 = 0, w1 = 0, w2 = 0;
#pragma unroll
    for (int j = 0; j < 4; ++j) {
      float p = (xs[j] + 2.2f) * 2.5f;
      float fl = floorf(p);
      int t0 = (int)fl;
      int idx = (int)((p - fl) * 256.0f) & 255;
      u64 codes = (u64)lut[idx];
      int sh = 6 * t0 - 18; // place c0 at slot t0-3
      u64 seg = (sh >= 0) ? (codes << sh) : (codes >> (-sh));
      seg = ((unsigned)t0 <= 10u) ? (seg & 0xFFFFFFFFFFFFULL) : 0ULL;
      if (j == 0) w0 |= seg;
      else if (j == 1) { w0 |= seg << 48; w1 |= seg >> 16; }
      else if (j == 2) { w1 |= seg << 32; w2 |= seg >> 32; }
      else             { w2 |= seg << 16; }
    }
    u64* dq = reinterpret_cast<u64*>(
        A2 + rb * RBSTRIDE + kb * KBBYTES + quad * (128 * GRANB) + r * GRANB);
    dq[0] = w0; dq[1] = w1; dq[2] = w2;
  } else {
    int g = (blockIdx.x - 8192) * 256 + threadIdx.x;
    int r = g & 127;
    int quad = (g >> 7) & 3;
    int kb = (g >> 9) & 63;
    int ob = g >> 15;
    long o = ob * 128 + r;
    int i0 = kb * 16 + quad * 4;

    float4 bw4 = *reinterpret_cast<const float4*>(bw + o * IN_FEAT + i0);
    union { __bf16 h[4]; u64 u; } b1;
    b1.h[0] = (__bf16)bw4.x; b1.h[1] = (__bf16)bw4.y;
    b1.h[2] = (__bf16)bw4.z; b1.h[3] = (__bf16)bw4.w;
    *reinterpret_cast<u64*>(B1 + o * IN_FEAT + i0) = b1.u;

    float vals[32];
    float4 sc4 = *reinterpret_cast<const float4*>(sc + o * IN_FEAT + i0);
    float scs[4] = {sc4.x, sc4.y, sc4.z, sc4.w};
#pragma unroll
    for (int j = 0; j < 4; ++j) {
      float scale = scs[j] * 256.0f; // 2^8, undone by scaleB=119
      const float4* sp =
          reinterpret_cast<const float4*>(sw + (o * IN_FEAT + i0 + j) * 8);
      float4 p0 = sp[0];
      float4 p1 = sp[1];
      vals[j * 8 + 0] = p0.x * scale; vals[j * 8 + 1] = p0.y * scale;
      vals[j * 8 + 2] = p0.z * scale; vals[j * 8 + 3] = p0.w * scale;
      vals[j * 8 + 4] = p1.x * scale; vals[j * 8 + 5] = p1.y * scale;
      vals[j * 8 + 6] = p1.z * scale; vals[j * 8 + 7] = p1.w * scale;
    }
    pack32_fp6(vals, B2 + (long)ob * RBSTRIDE + kb * KBBYTES +
                         quad * (128 * GRANB) + r * GRANB);
  }
}

// Pipelined fused GEMM v3 — LDS-traffic reduction:
//  - 256 threads = 4 waves (2M x 2N), 128x128 tile, wave tile 64x64:
//    fragment duplication 3x -> 2x (reads 12.3 -> 8 MB/CU).
//  - 32x32-family MFMAs: mfma_scale_f32_32x32x64_f8f6f4 (fp6, ~25% faster than
//    16x16x128 per ubench) + mfma_f32_32x32x16_bf16 (K=16 matches per-iter
//    bf16 K). Fragment maps: row=lane&31, k-chunk=lane>>5; C/D per m74/m101.
//  - K-step 128, dbuf 2x32 KB = 64 KB -> 2 blocks/CU (cross-block overlap at
//    barriers, m114) on top of the counted-vmcnt pipeline.
//  - bf16 LDS as [khalf(2)][row(128)][16B] (linear global_load_lds dest,
//    4-way-minimum read conflicts).
__global__ __launch_bounds__(256, 2) void gemm_fused(const unsigned char* __restrict__ A2,
                                                     const unsigned char* __restrict__ B2,
                                                     const __bf16* __restrict__ A1,
                                                     const __bf16* __restrict__ B1,
                                                     float* __restrict__ C) {
  // per-buffer: As6 [0,12288) | Bs6 [12288,24576) | As1 [24576,28672)
  //             | Bs1 [28672,32768); two buffers = 64 KiB.
  __shared__ __attribute__((aligned(16))) unsigned char smem[65536];

  const int tid = threadIdx.x;
  // XCD swizzle: flat 0..511, xcd = flat&7 owns a contiguous swz strip.
  const int flat = blockIdx.y * gridDim.x + blockIdx.x;
  const int swz = (flat & 7) * 64 + (flat >> 3);
  const int bm = swz >> 3;  // 0..63
  const int bn = swz & 7;   // 0..7

  const int lane = tid & 63;
  const int w = tid >> 6;        // 0..3
  const int wm = (w & 1) * 64;
  const int wn = (w >> 1) * 64;
  const int l32 = lane & 31;
  const int hi = lane >> 5;      // 0/1 -> k-chunk

  const unsigned char* gA6 = A2 + (long)bm * RBSTRIDE + tid * 16;
  const unsigned char* gB6 = B2 + (long)bn * RBSTRIDE + tid * 16;
  // bf16 staging: thread t -> half = t>>7, row = t&127 (dest = t*16, linear)
  const __bf16* gA1 = A1 + (long)(bm * 128 + (tid & 127)) * KBASE + (tid >> 7) * 8;
  const __bf16* gB1 = B1 + (long)(bn * 128 + (tid & 127)) * KBASE + (tid >> 7) * 8;

  // per-thread LDS read bases (within buffer 0)
  const unsigned char* aG = smem + hi * 3072 + (wm + l32) * GRANB;
  const unsigned char* bG = smem + 12288 + hi * 3072 + (wn + l32) * GRANB;
  const unsigned char* aH = smem + 24576 + hi * 2048 + (wm + l32) * 16;
  const unsigned char* bH = smem + 28672 + hi * 2048 + (wn + l32) * 16;

  v16f acc[2][2] = {};

  auto stage = [&](int it) {
    unsigned char* db = smem + (size_t)(it & 1) * 32768;
    const long off6 = (long)it * KBBYTES;
#pragma unroll
    for (int t = 0; t < 3; ++t) {
      load16_lds(gA6 + off6 + t * 4096, db + tid * 16 + t * 4096);
      load16_lds(gB6 + off6 + t * 4096, db + 12288 + tid * 16 + t * 4096);
    }
    const int k0 = it * 16;
    load16_lds(gA1 + k0, db + 24576 + tid * 16);
    load16_lds(gB1 + k0, db + 28672 + tid * 16);
  };

  auto compute = [&](int it) {
    const size_t bo = (size_t)(it & 1) * 32768;
    // fp6: 2 x 64-k steps; granule quad = 2*s + hi, row = wm/wn + mi*32 + l32
#pragma unroll
    for (int s = 0; s < 2; ++s) {
      v8i af[2], bf[2];
#pragma unroll
      for (int mi = 0; mi < 2; ++mi) {
        const unsigned char* rb = aG + bo + s * 6144 + mi * (32 * GRANB);
        u64 a0 = *reinterpret_cast<const u64*>(rb);
        u64 a1v = *reinterpret_cast<const u64*>(rb + 8);
        u64 a2v = *reinterpret_cast<const u64*>(rb + 16);
        v8i f = {(int)a0, (int)(a0 >> 32), (int)a1v, (int)(a1v >> 32),
                 (int)a2v, (int)(a2v >> 32), 0, 0};
        af[mi] = f;
      }
#pragma unroll
      for (int ni = 0; ni < 2; ++ni) {
        const unsigned char* rb = bG + bo + s * 6144 + ni * (32 * GRANB);
        u64 b0 = *reinterpret_cast<const u64*>(rb);
        u64 b1v = *reinterpret_cast<const u64*>(rb + 8);
        u64 b2v = *reinterpret_cast<const u64*>(rb + 16);
        v8i f = {(int)b0, (int)(b0 >> 32), (int)b1v, (int)(b1v >> 32),
                 (int)b2v, (int)(b2v >> 32), 0, 0};
        bf[ni] = f;
      }
      __builtin_amdgcn_s_setprio(1);
#pragma unroll
      for (int mi = 0; mi < 2; ++mi)
#pragma unroll
        for (int ni = 0; ni < 2; ++ni)
          // fmt 2 = fp6 e2m3 both; scaleA=125 (2^-2), scaleB=119 (2^-8)
          acc[mi][ni] = __builtin_amdgcn_mfma_scale_f32_32x32x64_f8f6f4(
              af[mi], bf[ni], acc[mi][ni], 2, 2, 0, 125, 0, 119);
      __builtin_amdgcn_s_setprio(0);
    }
    // bf16: one 32x32x16 k-step (k = hi*8 + e)
    {
      v8bf a1f[2], b1f[2];
#pragma unroll
      for (int mi = 0; mi < 2; ++mi)
        a1f[mi] = *reinterpret_cast<const v8bf*>(aH + bo + mi * (32 * 16));
#pragma unroll
      for (int ni = 0; ni < 2; ++ni)
        b1f[ni] = *reinterpret_cast<const v8bf*>(bH + bo + ni * (32 * 16));
      __builtin_amdgcn_s_setprio(1);
#pragma unroll
      for (int mi = 0; mi < 2; ++mi)
#pragma unroll
        for (int ni = 0; ni < 2; ++ni)
          acc[mi][ni] = __builtin_amdgcn_mfma_f32_32x32x16_bf16(
              a1f[mi], b1f[ni], acc[mi][ni], 0, 0, 0);
      __builtin_amdgcn_s_setprio(0);
    }
  };

#define VM_WAIT8() asm volatile("s_waitcnt vmcnt(8)" ::: "memory")
#define VM_WAIT0() asm volatile("s_waitcnt vmcnt(0)" ::: "memory")
#define LGKM0()    asm volatile("s_waitcnt lgkmcnt(0)" ::: "memory")
#define BARRIER()  asm volatile("s_barrier" ::: "memory")

  stage(0);
#pragma unroll 1
  for (int it = 0; it < 63; ++it) {
    stage(it + 1);
    VM_WAIT8();   // waits only tile-it's 8 loads; it+1's stay in flight
    BARRIER();
    compute(it);
    LGKM0();      // all ds_reads retired before next stage overwrites buffer
    BARRIER();
  }
  VM_WAIT0();
  BARRIER();
  compute(63);

  // Epilogue: 32x32 C/D layout (m74/m101): col = lane&31,
  // row = (reg&3) + 8*(reg>>2) + 4*(lane>>5).
#pragma unroll
  for (int mi = 0; mi < 2; ++mi)
#pragma unroll
    for (int ni = 0; ni < 2; ++ni)
#pragma unroll
      for (int r = 0; r < 16; ++r) {
        int row = bm * 128 + wm + mi * 32 + (r & 3) + 8 * (r >> 2) + 4 * hi;
        int col = bn * 128 + wn + ni * 32 + l32;
        C[(long)row * OUT_FEAT + col] = acc[mi][ni][r];
      }
}

extern "C" void kernel_launch(void* const* d_in, const int* in_sizes, int n_in,
                              void* d_out, int out_size, void* d_ws, size_t ws_size,
                              hipStream_t stream) {
  const float* x = (const float*)d_in[0];
  const float* bw = (const float*)d_in[1];
  const float* sw = (const float*)d_in[2];
  const float* sc = (const float*)d_in[3];
  const float* grid = (const float*)d_in[4];
  float* out = (float*)d_out;

  // ws: A1 bf16 16.8MB | A2 fp6 50.3MB | B1 bf16 2MB | B2 fp6 6.3MB
  __bf16* A1 = (__bf16*)d_ws;
  unsigned char* A2 = (unsigned char*)(A1 + (size_t)NSAMP * KBASE);
  __bf16* B1 = (__bf16*)(A2 + 64L * RBSTRIDE);
  unsigned char* B2 = (unsigned char*)(B1 + (size_t)OUT_FEAT * KBASE);

  build_AB<<<8192 + 1024, 256, 0, stream>>>(x, grid, bw, sw, sc, A1, A2, B1, B2);
  gemm_fused<<<dim3(NSAMP / 128, OUT_FEAT / 128), 256, 0, stream>>>(
      A2, B2, A1, B1, out);
}